// Round 1
// baseline (573.959 us; speedup 1.0000x reference)
//
#include <hip/hip_runtime.h>

#define DIM 64

static __device__ __forceinline__ int lower_bound(const int* __restrict__ a, int n, int v) {
    int lo = 0, hi = n;
    while (lo < hi) {
        int m = (lo + hi) >> 1;
        if (a[m] < v) lo = m + 1; else hi = m;
    }
    return lo;
}

// One wave (64 lanes) per batch sample; lane = embedding dim.
// 256-thread block = 4 samples. Gather of one feat row = 64 lanes x 4B
// = 256B fully coalesced.
__global__ __launch_bounds__(256) void mf_fwd_kernel(
    const int* __restrict__ user_ids, const int* __restrict__ item_ids,
    const int* __restrict__ u_idx, const float* __restrict__ u_val,
    const int* __restrict__ u_seg,
    const int* __restrict__ i_idx, const float* __restrict__ i_val,
    const int* __restrict__ i_seg,
    const float* __restrict__ user_emb, const float* __restrict__ item_emb,
    const float* __restrict__ ufeat_emb, const float* __restrict__ ifeat_emb,
    const float* __restrict__ user_bias, const float* __restrict__ item_bias,
    const float* __restrict__ global_bias,
    float* __restrict__ out,
    int batch, int Tu, int Ti)
{
    const int lane = threadIdx.x & 63;
    const int wave = threadIdx.x >> 6;
    const int b = (blockIdx.x << 2) + wave;
    if (b >= batch) return;

    // Segment bounds: seg arrays are sorted, binary search is ~20 uniform steps.
    // readfirstlane => wave-uniform loop bounds so idx/val loads can scalarize.
    int us  = __builtin_amdgcn_readfirstlane(lower_bound(u_seg, Tu, b));
    int ue  = __builtin_amdgcn_readfirstlane(lower_bound(u_seg, Tu, b + 1));
    int is0 = __builtin_amdgcn_readfirstlane(lower_bound(i_seg, Ti, b));
    int ie  = __builtin_amdgcn_readfirstlane(lower_bound(i_seg, Ti, b + 1));

    const int uid = user_ids[b];
    const int iid = item_ids[b];

    float u = user_emb[(size_t)uid * DIM + lane];
    for (int t = us; t < ue; ++t) {
        int   r = u_idx[t];
        float w = u_val[t];
        u = fmaf(ufeat_emb[(size_t)r * DIM + lane], w, u);
    }

    float v = item_emb[(size_t)iid * DIM + lane];
    for (int t = is0; t < ie; ++t) {
        int   r = i_idx[t];
        float w = i_val[t];
        v = fmaf(ifeat_emb[(size_t)r * DIM + lane], w, v);
    }

    float p = u * v;
    #pragma unroll
    for (int off = 32; off > 0; off >>= 1)
        p += __shfl_xor(p, off, 64);

    if (lane == 0)
        out[b] = p + user_bias[uid] + item_bias[iid] + global_bias[0];
}

extern "C" void kernel_launch(void* const* d_in, const int* in_sizes, int n_in,
                              void* d_out, int out_size, void* d_ws, size_t ws_size,
                              hipStream_t stream) {
    const int*   user_ids    = (const int*)d_in[0];
    const int*   item_ids    = (const int*)d_in[1];
    const int*   u_idx       = (const int*)d_in[2];
    const float* u_val       = (const float*)d_in[3];
    const int*   u_seg       = (const int*)d_in[4];
    const int*   i_idx       = (const int*)d_in[5];
    const float* i_val       = (const float*)d_in[6];
    const int*   i_seg       = (const int*)d_in[7];
    const float* user_emb    = (const float*)d_in[8];
    const float* item_emb    = (const float*)d_in[9];
    const float* ufeat_emb   = (const float*)d_in[10];
    const float* ifeat_emb   = (const float*)d_in[11];
    const float* user_bias   = (const float*)d_in[12];
    const float* item_bias   = (const float*)d_in[13];
    const float* global_bias = (const float*)d_in[14];
    float* out = (float*)d_out;

    const int batch = in_sizes[0];
    const int Tu    = in_sizes[2];
    const int Ti    = in_sizes[5];

    const int blocks = (batch + 3) / 4;
    mf_fwd_kernel<<<blocks, 256, 0, stream>>>(
        user_ids, item_ids, u_idx, u_val, u_seg, i_idx, i_val, i_seg,
        user_emb, item_emb, ufeat_emb, ifeat_emb, user_bias, item_bias,
        global_bias, out, batch, Tu, Ti);
}

// Round 2
// 518.559 us; speedup vs baseline: 1.1068x; 1.1068x over previous
//
#include <hip/hip_runtime.h>

#define DIM 64
#define TBATCH 8   // gathers kept in flight per wave per table loop

static __device__ __forceinline__ int lower_bound(const int* __restrict__ a, int n, int v) {
    int lo = 0, hi = n;
    while (lo < hi) {
        int m = (lo + hi) >> 1;
        if (a[m] < v) lo = m + 1; else hi = m;
    }
    return lo;
}

// Weighted segment-sum over [ts, te) of table rows, batched TBATCH deep so
// TBATCH independent 256B row-gathers are outstanding at once (breaks the
// idx-load -> row-load serial chain that limited round 1 to 0.35
// outstanding loads/wave).
static __device__ __forceinline__ float ragged_accum(
    float acc, const float* __restrict__ table,
    const int* __restrict__ idx, const float* __restrict__ val,
    int ts, int te, int lane)
{
    int t = ts;
    for (; t + TBATCH <= te; t += TBATCH) {
        int   r[TBATCH];
        float w[TBATCH];
        #pragma unroll
        for (int j = 0; j < TBATCH; ++j) { r[j] = idx[t + j]; w[j] = val[t + j]; }
        float row[TBATCH];
        #pragma unroll
        for (int j = 0; j < TBATCH; ++j)
            row[j] = table[(size_t)r[j] * DIM + lane];
        #pragma unroll
        for (int j = 0; j < TBATCH; ++j)
            acc = fmaf(row[j], w[j], acc);
    }
    for (; t < te; ++t)
        acc = fmaf(table[(size_t)idx[t] * DIM + lane], val[t], acc);
    return acc;
}

// One wave (64 lanes) per batch sample; lane = embedding dim.
__global__ __launch_bounds__(256) void mf_fwd_kernel(
    const int* __restrict__ user_ids, const int* __restrict__ item_ids,
    const int* __restrict__ u_idx, const float* __restrict__ u_val,
    const int* __restrict__ u_seg,
    const int* __restrict__ i_idx, const float* __restrict__ i_val,
    const int* __restrict__ i_seg,
    const float* __restrict__ user_emb, const float* __restrict__ item_emb,
    const float* __restrict__ ufeat_emb, const float* __restrict__ ifeat_emb,
    const float* __restrict__ user_bias, const float* __restrict__ item_bias,
    const float* __restrict__ global_bias,
    float* __restrict__ out,
    int batch, int Tu, int Ti)
{
    const int lane = threadIdx.x & 63;
    const int wave = threadIdx.x >> 6;
    const int b = (blockIdx.x << 2) + wave;
    if (b >= batch) return;

    // Wave-uniform segment bounds (sorted seg arrays, ~20 uniform bsearch steps).
    int us  = __builtin_amdgcn_readfirstlane(lower_bound(u_seg, Tu, b));
    int ue  = __builtin_amdgcn_readfirstlane(lower_bound(u_seg, Tu, b + 1));
    int is0 = __builtin_amdgcn_readfirstlane(lower_bound(i_seg, Ti, b));
    int ie  = __builtin_amdgcn_readfirstlane(lower_bound(i_seg, Ti, b + 1));

    const int uid = user_ids[b];
    const int iid = item_ids[b];

    // Issue both dense-row loads up front (independent of the token loops).
    float u0 = user_emb[(size_t)uid * DIM + lane];
    float v0 = item_emb[(size_t)iid * DIM + lane];

    float u = ragged_accum(u0, ufeat_emb, u_idx, u_val, us,  ue, lane);
    float v = ragged_accum(v0, ifeat_emb, i_idx, i_val, is0, ie, lane);

    float p = u * v;
    #pragma unroll
    for (int off = 32; off > 0; off >>= 1)
        p += __shfl_xor(p, off, 64);

    if (lane == 0)
        out[b] = p + user_bias[uid] + item_bias[iid] + global_bias[0];
}

extern "C" void kernel_launch(void* const* d_in, const int* in_sizes, int n_in,
                              void* d_out, int out_size, void* d_ws, size_t ws_size,
                              hipStream_t stream) {
    const int*   user_ids    = (const int*)d_in[0];
    const int*   item_ids    = (const int*)d_in[1];
    const int*   u_idx       = (const int*)d_in[2];
    const float* u_val       = (const float*)d_in[3];
    const int*   u_seg       = (const int*)d_in[4];
    const int*   i_idx       = (const int*)d_in[5];
    const float* i_val       = (const float*)d_in[6];
    const int*   i_seg       = (const int*)d_in[7];
    const float* user_emb    = (const float*)d_in[8];
    const float* item_emb    = (const float*)d_in[9];
    const float* ufeat_emb   = (const float*)d_in[10];
    const float* ifeat_emb   = (const float*)d_in[11];
    const float* user_bias   = (const float*)d_in[12];
    const float* item_bias   = (const float*)d_in[13];
    const float* global_bias = (const float*)d_in[14];
    float* out = (float*)d_out;

    const int batch = in_sizes[0];
    const int Tu    = in_sizes[2];
    const int Ti    = in_sizes[5];

    const int blocks = (batch + 3) / 4;
    mf_fwd_kernel<<<blocks, 256, 0, stream>>>(
        user_ids, item_ids, u_idx, u_val, u_seg, i_idx, i_val, i_seg,
        user_emb, item_emb, ufeat_emb, ifeat_emb, user_bias, item_bias,
        global_bias, out, batch, Tu, Ti);
}